// Round 6
// baseline (96.510 us; speedup 1.0000x reference)
//
#include <hip/hip_runtime.h>
#include <hip/hip_bf16.h>
#include <hip/hip_fp16.h>
#include <math.h>

// R18: occupancy + MFMA-floor package (post-mortem of R17: af-VALU cut gave
// exactly its arithmetic (-2.6us) -> dominant cost is the latency bucket at
// 4 blocks/CU (grid-capped 50% occupancy) + MFMA floor (incl. ones-MFMA).
//  1) attn blocks 64->32 i-rows: 2048 blocks = 8 blocks/CU = 100% occupancy.
//  2) exp tables folded into gemm epilogue (BpH/BnH f16 in ws, sdT dropped);
//     attn phase-0 = Bp-max + log2f (log2-domain shift cancels in softmax).
//  3) denominator via v_dot2_f32_f16 on af fragments (guarded) instead of
//     ones-MFMA: MFMA/SIMD floor 4.1 -> 2.1 us, frees 16 acc VGPRs.
//  4) LDS 33 -> 9 KB, launch_bounds(256,8).

// Problem constants
#define F_IN  256
#define NOUT  256          // N_HEADS * N_HIDDEN
#define NB    8            // batch
#define NN    1024         // nodes
#define NH    8            // heads
#define ND    32           // hidden per head
#define NROWS (NB * NN)    // 8192
#define LOG2E 1.44269504f

typedef __attribute__((ext_vector_type(8))) short bf16x8;       // 8 bf16
typedef __attribute__((ext_vector_type(8))) _Float16 f16x8;     // 8 f16
typedef __attribute__((ext_vector_type(2))) _Float16 f16x2;     // packed f16
typedef __attribute__((ext_vector_type(4))) float f32x4;        // MFMA C/D

__device__ inline unsigned pk_bf16(float a, float b) {
    union { __hip_bfloat162 h2; unsigned u; } c;
    c.h2 = __float22bfloat162_rn(make_float2(a, b));
    return c.u;
}
__device__ inline unsigned pk_f16(float a, float b) {
    union { __half2 h2; unsigned u; } c;
    c.h2 = __float22half2_rn(make_float2(a, b));
    return c.u;
}
__device__ inline unsigned short f16b(float x) {
    union { __half h; unsigned short u; } c;
    c.h = __float2half(x);
    return c.u;
}
__device__ inline float h2f(unsigned short u) {
    union { unsigned short u; __half h; } c;
    c.u = u;
    return __half2float(c.h);
}

#if __has_builtin(__builtin_amdgcn_fdot2)
__device__ __forceinline__ float fdot2acc(f16x2 a, f16x2 b, float c) {
    return __builtin_amdgcn_fdot2(a, b, c, false);
}
#else
__device__ __forceinline__ float fdot2acc(f16x2 a, f16x2 b, float c) {
    return c + (float)a.x * (float)b.x + (float)a.y * (float)b.y;
}
#endif

// truncation-based hi/lo split (RZ hi via mask; lo = a-hi is exact fp32)
__device__ inline void split8(const float4 va, const float4 vb,
                              bf16x8& hi, bf16x8& lo) {
    float f[8] = {va.x, va.y, va.z, va.w, vb.x, vb.y, vb.z, vb.w};
    union { bf16x8 v; unsigned u[4]; } H, L;
    #pragma unroll
    for (int i = 0; i < 4; ++i) {
        unsigned u0 = __float_as_uint(f[2 * i]);
        unsigned u1 = __float_as_uint(f[2 * i + 1]);
        unsigned h0 = u0 & 0xFFFF0000u;
        unsigned h1 = u1 & 0xFFFF0000u;
        H.u[i] = (u0 >> 16) | h1;
        L.u[i] = pk_bf16(f[2 * i]     - __uint_as_float(h0),
                         f[2 * i + 1] - __uint_as_float(h1));
    }
    hi = H.v; lo = L.v;
}

// ---------------------------------------------------------------------------
// Kernel 1: g = vertex @ w_vert via split-bf16 MFMA, split-k 2-way.
// R18: epilogue additionally stores Bp=exp(sd), Bn=exp(0.2*sd) as f16 tables
// (replacing raw sdT); ssT stored as one float4 per lane-group.
// ---------------------------------------------------------------------------
__global__ __launch_bounds__(256, 4) void gat_gemm_kernel(
    const float* __restrict__ vertex, const float* __restrict__ w_vert,
    const float* __restrict__ attn_w, unsigned short* __restrict__ gT,
    float* __restrict__ ssT, unsigned short* __restrict__ BpH,
    unsigned short* __restrict__ BnH)
{
    __shared__ __align__(16) unsigned short bHi[8192];
    __shared__ __align__(16) unsigned short bLo[8192];
    f32x4 (*comb)[4][64] = reinterpret_cast<f32x4(*)[4][64]>(bHi);
    unsigned short (*trans)[72] = reinterpret_cast<unsigned short(*)[72]>(bLo);

    const int t = threadIdx.x, lane = t & 63, wv = t >> 6;
    const int mt = wv & 1, kh = wv >> 1;
    const int il = lane & 15, ql = lane >> 4;
    const int h = blockIdx.y, gr0 = blockIdx.x * 64;
    const int b = gr0 >> 10, bh = b * NH + h;

    {
        const int n  = t & 31;
        const int kb = t >> 5;               // 0..7
        const int il_s = n & 15, nt_s = n >> 4;
        #pragma unroll
        for (int q = 0; q < 4; ++q) {
            const int k0 = kb * 8 + 64 * q;  // 8-aligned, covers 0..255
            const float* wp = w_vert + (size_t)k0 * NOUT + h * 32 + n;
            float f[8];
            #pragma unroll
            for (int j = 0; j < 8; ++j) f[j] = wp[j * NOUT];
            unsigned hu[4], lu[4];
            #pragma unroll
            for (int j2 = 0; j2 < 4; ++j2) {
                unsigned u0 = __float_as_uint(f[2 * j2]);
                unsigned u1 = __float_as_uint(f[2 * j2 + 1]);
                unsigned h0 = u0 & 0xFFFF0000u;
                unsigned h1 = u1 & 0xFFFF0000u;
                hu[j2] = (u0 >> 16) | h1;
                lu[j2] = pk_bf16(f[2 * j2]     - __uint_as_float(h0),
                                 f[2 * j2 + 1] - __uint_as_float(h1));
            }
            const int ktile = k0 >> 5;           // 0..7
            const int qlb   = (k0 & 31) >> 3;    // 0..3
            const int off   = (ktile * 2 + nt_s) * 512 + (qlb * 16 + il_s) * 8;
            *(uint4*)&bHi[off] = *(const uint4*)hu;
            *(uint4*)&bLo[off] = *(const uint4*)lu;
        }
    }
    __syncthreads();

    const float* arow0 = vertex + (size_t)(gr0 + mt * 32 + il) * F_IN + kh * 128 + ql * 8;
    const float* arow1 = arow0 + 16 * F_IN;

    f32x4 c00 = {0.f, 0.f, 0.f, 0.f}, c01 = c00, c10 = c00, c11 = c00;

    #pragma unroll
    for (int kk = 0; kk < 4; ++kk) {
        float4 a0a = *(const float4*)(arow0 + kk * 32);
        float4 a0b = *(const float4*)(arow0 + kk * 32 + 4);
        float4 a1a = *(const float4*)(arow1 + kk * 32);
        float4 a1b = *(const float4*)(arow1 + kk * 32 + 4);

        const int bkb = (kh * 4 + kk) * 2;
        bf16x8 bh0 = *(const bf16x8*)&bHi[bkb * 512 + lane * 8];
        bf16x8 bh1 = *(const bf16x8*)&bHi[(bkb + 1) * 512 + lane * 8];
        bf16x8 bl0 = *(const bf16x8*)&bLo[bkb * 512 + lane * 8];
        bf16x8 bl1 = *(const bf16x8*)&bLo[(bkb + 1) * 512 + lane * 8];

        bf16x8 a0hi, a0lo, a1hi, a1lo;
        split8(a0a, a0b, a0hi, a0lo);
        split8(a1a, a1b, a1hi, a1lo);

        c00 = __builtin_amdgcn_mfma_f32_16x16x32_bf16(a0hi, bh0, c00, 0, 0, 0);
        c01 = __builtin_amdgcn_mfma_f32_16x16x32_bf16(a0hi, bh1, c01, 0, 0, 0);
        c10 = __builtin_amdgcn_mfma_f32_16x16x32_bf16(a1hi, bh0, c10, 0, 0, 0);
        c11 = __builtin_amdgcn_mfma_f32_16x16x32_bf16(a1hi, bh1, c11, 0, 0, 0);
        c00 = __builtin_amdgcn_mfma_f32_16x16x32_bf16(a0lo, bh0, c00, 0, 0, 0);
        c01 = __builtin_amdgcn_mfma_f32_16x16x32_bf16(a0lo, bh1, c01, 0, 0, 0);
        c10 = __builtin_amdgcn_mfma_f32_16x16x32_bf16(a1lo, bh0, c10, 0, 0, 0);
        c11 = __builtin_amdgcn_mfma_f32_16x16x32_bf16(a1lo, bh1, c11, 0, 0, 0);
        c00 = __builtin_amdgcn_mfma_f32_16x16x32_bf16(a0hi, bl0, c00, 0, 0, 0);
        c01 = __builtin_amdgcn_mfma_f32_16x16x32_bf16(a0hi, bl1, c01, 0, 0, 0);
        c10 = __builtin_amdgcn_mfma_f32_16x16x32_bf16(a1hi, bl0, c10, 0, 0, 0);
        c11 = __builtin_amdgcn_mfma_f32_16x16x32_bf16(a1hi, bl1, c11, 0, 0, 0);
    }

    __syncthreads();
    if (kh == 1) {
        comb[mt][0][lane] = c00; comb[mt][1][lane] = c01;
        comb[mt][2][lane] = c10; comb[mt][3][lane] = c11;
    }
    __syncthreads();
    if (kh == 0) {
        c00 = c00 + comb[mt][0][lane]; c01 = c01 + comb[mt][1][lane];
        c10 = c10 + comb[mt][2][lane]; c11 = c11 + comb[mt][3][lane];

        const float wsv0 = attn_w[il],      wsv1 = attn_w[16 + il];
        const float wdv0 = attn_w[ND + il], wdv1 = attn_w[ND + 16 + il];
        const int j0 = (gr0 & 1023) + mt * 32;

        #pragma unroll
        for (int g = 0; g < 2; ++g) {
            f32x4 cA = g ? c10 : c00;   // d = il
            f32x4 cB = g ? c11 : c01;   // d = 16+il
            const int jl = mt * 32 + g * 16 + ql * 4;   // local j in [0,64)

            // transpose into padded LDS — g stored as f16
            *(unsigned*)&trans[il][jl]          = pk_f16(cA[0], cA[1]);
            *(unsigned*)&trans[il][jl + 2]      = pk_f16(cA[2], cA[3]);
            *(unsigned*)&trans[16 + il][jl]     = pk_f16(cB[0], cB[1]);
            *(unsigned*)&trans[16 + il][jl + 2] = pk_f16(cB[2], cB[3]);

            const int jr = j0 + g * 16 + ql * 4;
            float psv[4];
            unsigned short bpv[4], bnv[4];
            #pragma unroll
            for (int reg = 0; reg < 4; ++reg) {
                float ps = cA[reg] * wsv0 + cB[reg] * wsv1;
                float pd = cA[reg] * wdv0 + cB[reg] * wdv1;
                #pragma unroll
                for (int off = 1; off < 16; off <<= 1) {
                    ps += __shfl_xor(ps, off);
                    pd += __shfl_xor(pd, off);
                }
                psv[reg] = ps;
                // exp tables from sd (all lanes compute; il==0 stores)
                bpv[reg] = f16b(exp2f(pd * LOG2E));
                bnv[reg] = f16b(exp2f(0.2f * LOG2E * pd));
            }
            if (il == 0) {
                *(float4*)(ssT + bh * NN + jr) =
                    make_float4(psv[0], psv[1], psv[2], psv[3]);
                *(ushort4*)(BpH + bh * NN + jr) =
                    make_ushort4(bpv[0], bpv[1], bpv[2], bpv[3]);
                *(ushort4*)(BnH + bh * NN + jr) =
                    make_ushort4(bnv[0], bnv[1], bnv[2], bnv[3]);
            }
        }
    }
    __syncthreads();

    {
        const int d  = t >> 3;
        const int jo = (t & 7) * 8;
        uint4 v = *(const uint4*)&trans[d][jo];
        *(uint4*)(gT + ((size_t)(bh * ND) + d) * NN + (gr0 & 1023) + jo) = v;
    }
}

// ---------------------------------------------------------------------------
// Kernel 2 (exp-free MFMA attn, R18 structure):
//   2048 blocks x 32 i-rows; 4 waves = j-quarters; 2 m-tiles/wave.
//   P_ij = max(ap_i*Bp_j, an_i*Bn_j) in packed f16; Bp/Bn/gT read straight
//   from global (L2-resident, XCD-affine via bid%8=h). Denominator via
//   fdot2 row-sums on af (A-frag row = lane&15), ql-reduce + shfl at end.
// ---------------------------------------------------------------------------
__global__ __launch_bounds__(256, 8) void gat_attn_kernel(
    const unsigned short* __restrict__ gT, const float* __restrict__ ssT,
    const unsigned short* __restrict__ BpH,
    const unsigned short* __restrict__ BnH, float* __restrict__ out)
{
    __shared__ f32x4 ccomb[2][4][64];   // 8 KB
    __shared__ float scomb[2][2][64];   // 1 KB
    __shared__ float red[4];

    const int bid = blockIdx.x;
    const int bh = bid & 63;                 // b*NH + h  (bid%8 = h)
    const int b = bh >> 3, h = bh & 7;
    const int i0 = (bid >> 6) * 32;
    const int t = threadIdx.x, lane = t & 63, jq = t >> 6;
    const int il = lane & 15, ql = lane >> 4;

    const unsigned short* bpb = BpH + (size_t)bh * NN;
    const unsigned short* bnb = BnH + (size_t)bh * NN;

    // ---- phase 0: M (log2 domain) from Bp table max ----
    float bm;
    {
        ushort4 v = *(const ushort4*)(bpb + t * 4);
        bm = fmaxf(fmaxf(h2f(v.x), h2f(v.y)), fmaxf(h2f(v.z), h2f(v.w)));
    }
    #pragma unroll
    for (int off = 32; off >= 1; off >>= 1)
        bm = fmaxf(bm, __shfl_xor(bm, off));
    if (lane == 0) red[jq] = bm;
    __syncthreads();
    bm = fmaxf(fmaxf(red[0], red[1]), fmaxf(red[2], red[3]));
    const float Mlog2 = log2f(bm);           // = M * LOG2E (f16-rounded;
                                             // per-row shift cancels in softmax)
    f16x2 apv[2], anv[2];
    #pragma unroll
    for (int mt = 0; mt < 2; ++mt) {
        const float si = ssT[bh * NN + i0 + mt * 16 + il];
        const float t2 = fmaf(si, LOG2E, Mlog2);
        const float mk = fmaxf(t2, 0.2f * t2);
        const _Float16 ah = (_Float16)exp2f(fmaf(si, LOG2E, -mk));
        const _Float16 nh = (_Float16)exp2f(fmaf(0.2f * si, LOG2E, -mk));
        apv[mt] = (f16x2){ah, ah};
        anv[mt] = (f16x2){nh, nh};
    }

    const unsigned short* gb0 = gT + ((size_t)(bh * ND) + il) * NN + jq * 256 + ql * 8;
    const unsigned short* gb1 = gb0 + 16 * NN;
    const unsigned short* bpq = bpb + jq * 256 + ql * 8;
    const unsigned short* bnq = bnb + jq * 256 + ql * 8;

    const f16x2 one2 = (f16x2){(_Float16)1.0f, (_Float16)1.0f};

    f32x4 c0[2], c1[2];
    float S[2] = {0.f, 0.f};
    #pragma unroll
    for (int mt = 0; mt < 2; ++mt) {
        c0[mt] = (f32x4){0.f, 0.f, 0.f, 0.f};
        c1[mt] = c0[mt];
    }

    // ---- main loop: wave jq handles j in [jq*256, jq*256+256) ----
    #pragma unroll 2
    for (int kk = 0; kk < 256; kk += 32) {
        union { uint4 q; unsigned w[4]; } pw, nw;
        pw.q = *(const uint4*)(bpq + kk);   // 8 packed f16 Bp
        nw.q = *(const uint4*)(bnq + kk);   // 8 packed f16 Bn
        const f16x8 bf0 = *(const f16x8*)(gb0 + kk);
        const f16x8 bf1 = *(const f16x8*)(gb1 + kk);

        #pragma unroll
        for (int mt = 0; mt < 2; ++mt) {
            union { f16x8 v; unsigned u[4]; } af;
            float s = S[mt];
            #pragma unroll
            for (int u = 0; u < 4; ++u) {
                union { unsigned w; f16x2 v; } p2, n2, e2;
                p2.w = pw.w[u];
                n2.w = nw.w[u];
                e2.v = __builtin_elementwise_max(p2.v * apv[mt],
                                                 n2.v * anv[mt]);
                af.u[u] = e2.w;
                s = fdot2acc(e2.v, one2, s);
            }
            S[mt] = s;
            c0[mt] = __builtin_amdgcn_mfma_f32_16x16x32_f16(af.v, bf0, c0[mt], 0, 0, 0);
            c1[mt] = __builtin_amdgcn_mfma_f32_16x16x32_f16(af.v, bf1, c1[mt], 0, 0, 0);
        }
    }

    // ---- quarter-combine tree: 2,3 -> 0,1; then 1 -> 0 ----
    if (jq >= 2) {
        #pragma unroll
        for (int mt = 0; mt < 2; ++mt) {
            ccomb[jq - 2][mt * 2 + 0][lane] = c0[mt];
            ccomb[jq - 2][mt * 2 + 1][lane] = c1[mt];
            scomb[jq - 2][mt][lane] = S[mt];
        }
    }
    __syncthreads();
    if (jq < 2) {
        #pragma unroll
        for (int mt = 0; mt < 2; ++mt) {
            c0[mt] = c0[mt] + ccomb[jq][mt * 2 + 0][lane];
            c1[mt] = c1[mt] + ccomb[jq][mt * 2 + 1][lane];
            S[mt] += scomb[jq][mt][lane];
        }
    }
    __syncthreads();
    if (jq == 1) {
        #pragma unroll
        for (int mt = 0; mt < 2; ++mt) {
            ccomb[0][mt * 2 + 0][lane] = c0[mt];
            ccomb[0][mt * 2 + 1][lane] = c1[mt];
            scomb[0][mt][lane] = S[mt];
        }
    }
    __syncthreads();
    if (jq == 0) {
        #pragma unroll
        for (int mt = 0; mt < 2; ++mt) {
            c0[mt] = c0[mt] + ccomb[0][mt * 2 + 0][lane];
            c1[mt] = c1[mt] + ccomb[0][mt * 2 + 1][lane];
            S[mt] += scomb[0][mt][lane];
            // S now full over j for row il, partial over ql j-slots -> reduce
            S[mt] += __shfl_xor(S[mt], 16);
            S[mt] += __shfl_xor(S[mt], 32);

            // C/D: col=il (d), row=ql*4+reg (i); S indexed by row via shfl
            float* ob = out + (size_t)(b * NN + i0 + mt * 16 + ql * 4) * NOUT + h * ND + il;
            #pragma unroll
            for (int reg = 0; reg < 4; ++reg) {
                const int rr = ql * 4 + reg;               // row within tile
                const float Srow = __shfl(S[mt], (ql << 4) | rr);
                const float r = 1.0f / Srow;
                ob[reg * NOUT]      = c0[mt][reg] * r;
                ob[reg * NOUT + 16] = c1[mt][reg] * r;
            }
        }
    }
}

// ---------------------------------------------------------------------------
extern "C" void kernel_launch(void* const* d_in, const int* in_sizes, int n_in,
                              void* d_out, int out_size, void* d_ws, size_t ws_size,
                              hipStream_t stream) {
    (void)in_sizes; (void)n_in; (void)out_size; (void)ws_size;
    const float* vertex = (const float*)d_in[0];
    const float* w_vert = (const float*)d_in[1];
    const float* attn_w = (const float*)d_in[2];
    float* out = (float*)d_out;

    char* ws = (char*)d_ws;
    unsigned short* gT = (unsigned short*)ws;                      // 4 MB
    char* p = ws + (size_t)NB * NH * ND * NN * 2;
    float* ssT = (float*)p;                                        // 256 KB
    p += (size_t)NB * NH * NN * 4;
    unsigned short* BpH = (unsigned short*)p;                      // 128 KB
    p += (size_t)NB * NH * NN * 2;
    unsigned short* BnH = (unsigned short*)p;                      // 128 KB

    gat_gemm_kernel<<<dim3(128, NH), 256, 0, stream>>>(vertex, w_vert, attn_w,
                                                       gT, ssT, BpH, BnH);
    gat_attn_kernel<<<2048, 256, 0, stream>>>(gT, ssT, BpH, BnH, out);
}

// Round 8
// 90.886 us; speedup vs baseline: 1.0619x; 1.0619x over previous
//
#include <hip/hip_runtime.h>
#include <hip/hip_bf16.h>
#include <hip/hip_fp16.h>
#include <math.h>

// R20: revert fusion (R19 raced: grid.sync() under graph capture did not
// order the gT handoff; absmax 0.375/468 run-variant). Back to R17 two-kernel
// structure. Single change vs R17: attn block 256->512 threads (8 waves =
// 2 i-halves x 4 j-quarters, 2 m-tiles/wave). Same 1024-block grid, same
// Bp/Bn LDS staging, same kk loop. Occupancy 4 -> 8 waves/SIMD (100%):
// attn was latency-bound (~16% issue utilization: modeled 2.2us issue vs
// 13.7us measured at 4 waves/SIMD). Predict T_a 13.7 -> ~8, dur ~80.

// Problem constants
#define F_IN  256
#define NOUT  256          // N_HEADS * N_HIDDEN
#define NB    8            // batch
#define NN    1024         // nodes
#define NH    8            // heads
#define ND    32           // hidden per head
#define NROWS (NB * NN)    // 8192
#define LOG2E 1.44269504f

typedef __attribute__((ext_vector_type(8))) short bf16x8;       // 8 bf16
typedef __attribute__((ext_vector_type(8))) _Float16 f16x8;     // 8 f16
typedef __attribute__((ext_vector_type(2))) _Float16 f16x2;     // packed f16
typedef __attribute__((ext_vector_type(4))) float f32x4;        // MFMA C/D

__device__ inline unsigned pk_bf16(float a, float b) {
    union { __hip_bfloat162 h2; unsigned u; } c;
    c.h2 = __float22bfloat162_rn(make_float2(a, b));
    return c.u;
}
__device__ inline unsigned pk_f16(float a, float b) {
    union { __half2 h2; unsigned u; } c;
    c.h2 = __float22half2_rn(make_float2(a, b));
    return c.u;
}
// truncation-based hi/lo split (RZ hi via mask; lo = a-hi is exact fp32)
__device__ inline void split8(const float4 va, const float4 vb,
                              bf16x8& hi, bf16x8& lo) {
    float f[8] = {va.x, va.y, va.z, va.w, vb.x, vb.y, vb.z, vb.w};
    union { bf16x8 v; unsigned u[4]; } H, L;
    #pragma unroll
    for (int i = 0; i < 4; ++i) {
        unsigned u0 = __float_as_uint(f[2 * i]);
        unsigned u1 = __float_as_uint(f[2 * i + 1]);
        unsigned h0 = u0 & 0xFFFF0000u;
        unsigned h1 = u1 & 0xFFFF0000u;
        H.u[i] = (u0 >> 16) | h1;
        L.u[i] = pk_bf16(f[2 * i]     - __uint_as_float(h0),
                         f[2 * i + 1] - __uint_as_float(h1));
    }
    hi = H.v; lo = L.v;
}

// ---------------------------------------------------------------------------
// Kernel 1: g = vertex @ w_vert via split-bf16 MFMA, split-k 2-way.
// Byte-identical to R17 (best-known gemm).
// ---------------------------------------------------------------------------
__global__ __launch_bounds__(256, 4) void gat_gemm_kernel(
    const float* __restrict__ vertex, const float* __restrict__ w_vert,
    const float* __restrict__ attn_w, unsigned short* __restrict__ gT,
    float* __restrict__ ssT, float* __restrict__ sdT)
{
    __shared__ __align__(16) unsigned short bHi[8192];
    __shared__ __align__(16) unsigned short bLo[8192];
    f32x4 (*comb)[4][64] = reinterpret_cast<f32x4(*)[4][64]>(bHi);
    unsigned short (*trans)[72] = reinterpret_cast<unsigned short(*)[72]>(bLo);

    const int t = threadIdx.x, lane = t & 63, wv = t >> 6;
    const int mt = wv & 1, kh = wv >> 1;
    const int il = lane & 15, ql = lane >> 4;
    const int h = blockIdx.y, gr0 = blockIdx.x * 64;
    const int b = gr0 >> 10, bh = b * NH + h;

    {
        const int n  = t & 31;
        const int kb = t >> 5;               // 0..7
        const int il_s = n & 15, nt_s = n >> 4;
        #pragma unroll
        for (int q = 0; q < 4; ++q) {
            const int k0 = kb * 8 + 64 * q;  // 8-aligned, covers 0..255
            const float* wp = w_vert + (size_t)k0 * NOUT + h * 32 + n;
            float f[8];
            #pragma unroll
            for (int j = 0; j < 8; ++j) f[j] = wp[j * NOUT];
            unsigned hu[4], lu[4];
            #pragma unroll
            for (int j2 = 0; j2 < 4; ++j2) {
                unsigned u0 = __float_as_uint(f[2 * j2]);
                unsigned u1 = __float_as_uint(f[2 * j2 + 1]);
                unsigned h0 = u0 & 0xFFFF0000u;
                unsigned h1 = u1 & 0xFFFF0000u;
                hu[j2] = (u0 >> 16) | h1;
                lu[j2] = pk_bf16(f[2 * j2]     - __uint_as_float(h0),
                                 f[2 * j2 + 1] - __uint_as_float(h1));
            }
            const int ktile = k0 >> 5;           // 0..7
            const int qlb   = (k0 & 31) >> 3;    // 0..3
            const int off   = (ktile * 2 + nt_s) * 512 + (qlb * 16 + il_s) * 8;
            *(uint4*)&bHi[off] = *(const uint4*)hu;
            *(uint4*)&bLo[off] = *(const uint4*)lu;
        }
    }
    __syncthreads();

    const float* arow0 = vertex + (size_t)(gr0 + mt * 32 + il) * F_IN + kh * 128 + ql * 8;
    const float* arow1 = arow0 + 16 * F_IN;

    f32x4 c00 = {0.f, 0.f, 0.f, 0.f}, c01 = c00, c10 = c00, c11 = c00;

    #pragma unroll
    for (int kk = 0; kk < 4; ++kk) {
        float4 a0a = *(const float4*)(arow0 + kk * 32);
        float4 a0b = *(const float4*)(arow0 + kk * 32 + 4);
        float4 a1a = *(const float4*)(arow1 + kk * 32);
        float4 a1b = *(const float4*)(arow1 + kk * 32 + 4);

        const int bkb = (kh * 4 + kk) * 2;
        bf16x8 bh0 = *(const bf16x8*)&bHi[bkb * 512 + lane * 8];
        bf16x8 bh1 = *(const bf16x8*)&bHi[(bkb + 1) * 512 + lane * 8];
        bf16x8 bl0 = *(const bf16x8*)&bLo[bkb * 512 + lane * 8];
        bf16x8 bl1 = *(const bf16x8*)&bLo[(bkb + 1) * 512 + lane * 8];

        bf16x8 a0hi, a0lo, a1hi, a1lo;
        split8(a0a, a0b, a0hi, a0lo);
        split8(a1a, a1b, a1hi, a1lo);

        c00 = __builtin_amdgcn_mfma_f32_16x16x32_bf16(a0hi, bh0, c00, 0, 0, 0);
        c01 = __builtin_amdgcn_mfma_f32_16x16x32_bf16(a0hi, bh1, c01, 0, 0, 0);
        c10 = __builtin_amdgcn_mfma_f32_16x16x32_bf16(a1hi, bh0, c10, 0, 0, 0);
        c11 = __builtin_amdgcn_mfma_f32_16x16x32_bf16(a1hi, bh1, c11, 0, 0, 0);
        c00 = __builtin_amdgcn_mfma_f32_16x16x32_bf16(a0lo, bh0, c00, 0, 0, 0);
        c01 = __builtin_amdgcn_mfma_f32_16x16x32_bf16(a0lo, bh1, c01, 0, 0, 0);
        c10 = __builtin_amdgcn_mfma_f32_16x16x32_bf16(a1lo, bh0, c10, 0, 0, 0);
        c11 = __builtin_amdgcn_mfma_f32_16x16x32_bf16(a1lo, bh1, c11, 0, 0, 0);
        c00 = __builtin_amdgcn_mfma_f32_16x16x32_bf16(a0hi, bl0, c00, 0, 0, 0);
        c01 = __builtin_amdgcn_mfma_f32_16x16x32_bf16(a0hi, bl1, c01, 0, 0, 0);
        c10 = __builtin_amdgcn_mfma_f32_16x16x32_bf16(a1hi, bl0, c10, 0, 0, 0);
        c11 = __builtin_amdgcn_mfma_f32_16x16x32_bf16(a1hi, bl1, c11, 0, 0, 0);
    }

    __syncthreads();
    if (kh == 1) {
        comb[mt][0][lane] = c00; comb[mt][1][lane] = c01;
        comb[mt][2][lane] = c10; comb[mt][3][lane] = c11;
    }
    __syncthreads();
    if (kh == 0) {
        c00 = c00 + comb[mt][0][lane]; c01 = c01 + comb[mt][1][lane];
        c10 = c10 + comb[mt][2][lane]; c11 = c11 + comb[mt][3][lane];

        const float wsv0 = attn_w[il],      wsv1 = attn_w[16 + il];
        const float wdv0 = attn_w[ND + il], wdv1 = attn_w[ND + 16 + il];
        const int j0 = (gr0 & 1023) + mt * 32;

        #pragma unroll
        for (int g = 0; g < 2; ++g) {
            f32x4 cA = g ? c10 : c00;   // d = il
            f32x4 cB = g ? c11 : c01;   // d = 16+il
            const int jl = mt * 32 + g * 16 + ql * 4;   // local j in [0,64)

            // transpose into padded LDS — g stored as f16
            *(unsigned*)&trans[il][jl]          = pk_f16(cA[0], cA[1]);
            *(unsigned*)&trans[il][jl + 2]      = pk_f16(cA[2], cA[3]);
            *(unsigned*)&trans[16 + il][jl]     = pk_f16(cB[0], cB[1]);
            *(unsigned*)&trans[16 + il][jl + 2] = pk_f16(cB[2], cB[3]);

            const int jr = j0 + g * 16 + ql * 4;
            #pragma unroll
            for (int reg = 0; reg < 4; ++reg) {
                float ps = cA[reg] * wsv0 + cB[reg] * wsv1;
                float pd = cA[reg] * wdv0 + cB[reg] * wdv1;
                #pragma unroll
                for (int off = 1; off < 16; off <<= 1) {
                    ps += __shfl_xor(ps, off);
                    pd += __shfl_xor(pd, off);
                }
                if (il == 0) {
                    ssT[bh * NN + jr + reg] = ps;
                    sdT[bh * NN + jr + reg] = pd;
                }
            }
        }
    }
    __syncthreads();

    {
        const int d  = t >> 3;
        const int jo = (t & 7) * 8;
        uint4 v = *(const uint4*)&trans[d][jo];
        *(uint4*)(gT + ((size_t)(bh * ND) + d) * NN + (gr0 & 1023) + jo) = v;
    }
}

// ---------------------------------------------------------------------------
// Kernel 2 (exp-free MFMA attn, packed-f16 P path, R20 8-wave layout):
//   1024 blocks x 512 threads; wave wv = (ih = wv>>2, jq = wv&3).
//   Wave (ih,jq): m-tiles {ih*2, ih*2+1} x j-quarter jq — same kk loop as
//   R17, half the m-tiles, double the resident waves (8/SIMD = 100% occ).
// ---------------------------------------------------------------------------
__global__ __launch_bounds__(512, 8) void gat_attn_kernel(
    const unsigned short* __restrict__ gT, const float* __restrict__ ssT,
    const float* __restrict__ sdT, float* __restrict__ out)
{
    __shared__ __align__(16) unsigned short BpH[NN];   // 2 KB, f16 bits
    __shared__ __align__(16) unsigned short BnH[NN];   // 2 KB, f16 bits
    __shared__ f32x4 ccomb[2][2][6][64];               // 24 KB [ih][bank][reg][lane]
    __shared__ float red[8];

    const int bid = blockIdx.x;
    const int bh = bid & 63;                 // b*NH + h  (bid%8 = h)
    const int b = bh >> 3, h = bh & 7;
    const int i0 = (bid >> 6) * 64;
    const int t = threadIdx.x, lane = t & 63, wv = t >> 6;
    const int ih = wv >> 2, jq = wv & 3;
    const int il = lane & 15, ql = lane >> 4;

    // ---- phase 0: BpH/BnH (f16) + global sd max + per-lane i-constants ----
    float sdv[2]; float M = -3.0e38f;
    #pragma unroll
    for (int q = 0; q < 2; ++q) {
        sdv[q] = sdT[bh * NN + t + 512 * q];
        M = fmaxf(M, sdv[q]);
    }
    #pragma unroll
    for (int off = 32; off >= 1; off >>= 1)
        M = fmaxf(M, __shfl_xor(M, off));
    if (lane == 0) red[wv] = M;
    #pragma unroll
    for (int q = 0; q < 2; ++q) {
        union { _Float16 h; unsigned short u; } cp, cn;
        cp.h = (_Float16)exp2f(sdv[q] * LOG2E);
        cn.h = (_Float16)exp2f(0.2f * LOG2E * sdv[q]);
        BpH[t + 512 * q] = cp.u;
        BnH[t + 512 * q] = cn.u;
    }
    __syncthreads();
    M = fmaxf(fmaxf(fmaxf(red[0], red[1]), fmaxf(red[2], red[3])),
              fmaxf(fmaxf(red[4], red[5]), fmaxf(red[6], red[7])));

    f16x2 apv[2], anv[2];
    #pragma unroll
    for (int m = 0; m < 2; ++m) {
        const float si = ssT[bh * NN + i0 + (ih * 2 + m) * 16 + il];
        float x = si + M; x = fmaxf(x, 0.2f * x);
        const float mk = x * LOG2E;
        const _Float16 ah = (_Float16)exp2f(fmaf(si, LOG2E, -mk));
        const _Float16 nh = (_Float16)exp2f(fmaf(0.2f * si, LOG2E, -mk));
        apv[m] = (f16x2){ah, ah};
        anv[m] = (f16x2){nh, nh};
    }

    const unsigned short* gb0 = gT + ((size_t)(bh * ND) + il) * NN + jq * 256 + ql * 8;
    const unsigned short* gb1 = gb0 + 16 * NN;
    const unsigned short* bpq = BpH + jq * 256 + ql * 8;
    const unsigned short* bnq = BnH + jq * 256 + ql * 8;

    union { f16x8 v; unsigned u[4]; } ones;
    ones.u[0] = ones.u[1] = ones.u[2] = ones.u[3] = 0x3C003C00u;   // f16 1.0

    f32x4 c0[2], c1[2], cs[2];
    #pragma unroll
    for (int m = 0; m < 2; ++m) {
        c0[m] = (f32x4){0.f, 0.f, 0.f, 0.f};
        c1[m] = c0[m]; cs[m] = c0[m];
    }

    // ---- main loop: wave (ih,jq) handles j in [jq*256, jq*256+256) ----
    #pragma unroll 2
    for (int kk = 0; kk < 256; kk += 32) {
        union { uint4 q; unsigned w[4]; } pw, nw;
        pw.q = *(const uint4*)(bpq + kk);   // 8 packed f16 Bp
        nw.q = *(const uint4*)(bnq + kk);   // 8 packed f16 Bn
        const f16x8 bf0 = *(const f16x8*)(gb0 + kk);
        const f16x8 bf1 = *(const f16x8*)(gb1 + kk);

        #pragma unroll
        for (int m = 0; m < 2; ++m) {
            union { f16x8 v; unsigned u[4]; } af;
            #pragma unroll
            for (int u = 0; u < 4; ++u) {
                union { unsigned w; f16x2 v; } p2, n2, e2;
                p2.w = pw.w[u];
                n2.w = nw.w[u];
                e2.v = __builtin_elementwise_max(p2.v * apv[m],
                                                 n2.v * anv[m]);
                af.u[u] = e2.w;
            }
            c0[m] = __builtin_amdgcn_mfma_f32_16x16x32_f16(af.v, bf0, c0[m], 0, 0, 0);
            c1[m] = __builtin_amdgcn_mfma_f32_16x16x32_f16(af.v, bf1, c1[m], 0, 0, 0);
            cs[m] = __builtin_amdgcn_mfma_f32_16x16x32_f16(af.v, ones.v, cs[m], 0, 0, 0);
        }
    }

    // ---- quarter-combine tree per ih: jq 2,3 -> 0,1; then 1 -> 0 ----
    if (jq >= 2) {
        #pragma unroll
        for (int m = 0; m < 2; ++m) {
            ccomb[ih][jq - 2][m * 3 + 0][lane] = c0[m];
            ccomb[ih][jq - 2][m * 3 + 1][lane] = c1[m];
            ccomb[ih][jq - 2][m * 3 + 2][lane] = cs[m];
        }
    }
    __syncthreads();
    if (jq < 2) {
        #pragma unroll
        for (int m = 0; m < 2; ++m) {
            c0[m] = c0[m] + ccomb[ih][jq][m * 3 + 0][lane];
            c1[m] = c1[m] + ccomb[ih][jq][m * 3 + 1][lane];
            cs[m] = cs[m] + ccomb[ih][jq][m * 3 + 2][lane];
        }
    }
    __syncthreads();
    if (jq == 1) {
        #pragma unroll
        for (int m = 0; m < 2; ++m) {
            ccomb[ih][0][m * 3 + 0][lane] = c0[m];
            ccomb[ih][0][m * 3 + 1][lane] = c1[m];
            ccomb[ih][0][m * 3 + 2][lane] = cs[m];
        }
    }
    __syncthreads();
    if (jq == 0) {
        #pragma unroll
        for (int m = 0; m < 2; ++m) {
            c0[m] = c0[m] + ccomb[ih][0][m * 3 + 0][lane];
            c1[m] = c1[m] + ccomb[ih][0][m * 3 + 1][lane];
            cs[m] = cs[m] + ccomb[ih][0][m * 3 + 2][lane];

            // C/D: col=il (d), row=ql*4+reg (i); cs[m][reg] = S_i
            float* ob = out + (size_t)(b * NN + i0 + ih * 32 + m * 16 + ql * 4) * NOUT
                        + h * ND + il;
            #pragma unroll
            for (int reg = 0; reg < 4; ++reg) {
                const float r = 1.0f / cs[m][reg];
                ob[reg * NOUT]      = c0[m][reg] * r;
                ob[reg * NOUT + 16] = c1[m][reg] * r;
            }
        }
    }
}

// ---------------------------------------------------------------------------
extern "C" void kernel_launch(void* const* d_in, const int* in_sizes, int n_in,
                              void* d_out, int out_size, void* d_ws, size_t ws_size,
                              hipStream_t stream) {
    (void)in_sizes; (void)n_in; (void)out_size; (void)ws_size;
    const float* vertex = (const float*)d_in[0];
    const float* w_vert = (const float*)d_in[1];
    const float* attn_w = (const float*)d_in[2];
    float* out = (float*)d_out;

    char* ws = (char*)d_ws;
    unsigned short* gT = (unsigned short*)ws;                          // 4 MB
    float* ssT = (float*)(ws + ((size_t)NB * NH * ND * NN * 2));
    float* sdT = ssT + (size_t)NB * NH * NN;

    gat_gemm_kernel<<<dim3(128, NH), 256, 0, stream>>>(vertex, w_vert, attn_w,
                                                       gT, ssT, sdT);
    gat_attn_kernel<<<1024, 512, 0, stream>>>(gT, ssT, sdT, out);
}

// Round 9
// 85.120 us; speedup vs baseline: 1.1338x; 1.0677x over previous
//
#include <hip/hip_runtime.h>
#include <hip/hip_bf16.h>
#include <hip/hip_fp16.h>
#include <math.h>

// R21: revert R20 (8-wave split doubled gT L2 traffic: gb* depends only on
// (bh,il,jq) so both ih-halves loaded identical data; occupancy gain < BW
// loss). Back to R17 structure (best 85.2us). Single change: attn kk-loop
// software-pipelined with explicit rotating buffers — global gT prefetch
// depth 4 (16 L2 loads in flight/SIMD at 4 waves), LDS Bp/Bn depth 2.
// All pipes were <=15% utilized (VALU 1.3us, MFMA 0.8, LDS 0.9, L2 2.0 vs
// 13.7 measured) -> latency-bound with shallow ILP; this quadruples
// load-level parallelism at constant traffic. ~108 VGPR < 128 cap.

// Problem constants
#define F_IN  256
#define NOUT  256          // N_HEADS * N_HIDDEN
#define NB    8            // batch
#define NN    1024         // nodes
#define NH    8            // heads
#define ND    32           // hidden per head
#define NROWS (NB * NN)    // 8192
#define LOG2E 1.44269504f

typedef __attribute__((ext_vector_type(8))) short bf16x8;       // 8 bf16
typedef __attribute__((ext_vector_type(8))) _Float16 f16x8;     // 8 f16
typedef __attribute__((ext_vector_type(2))) _Float16 f16x2;     // packed f16
typedef __attribute__((ext_vector_type(4))) float f32x4;        // MFMA C/D

__device__ inline unsigned pk_bf16(float a, float b) {
    union { __hip_bfloat162 h2; unsigned u; } c;
    c.h2 = __float22bfloat162_rn(make_float2(a, b));
    return c.u;
}
__device__ inline unsigned pk_f16(float a, float b) {
    union { __half2 h2; unsigned u; } c;
    c.h2 = __float22half2_rn(make_float2(a, b));
    return c.u;
}
// truncation-based hi/lo split (RZ hi via mask; lo = a-hi is exact fp32)
__device__ inline void split8(const float4 va, const float4 vb,
                              bf16x8& hi, bf16x8& lo) {
    float f[8] = {va.x, va.y, va.z, va.w, vb.x, vb.y, vb.z, vb.w};
    union { bf16x8 v; unsigned u[4]; } H, L;
    #pragma unroll
    for (int i = 0; i < 4; ++i) {
        unsigned u0 = __float_as_uint(f[2 * i]);
        unsigned u1 = __float_as_uint(f[2 * i + 1]);
        unsigned h0 = u0 & 0xFFFF0000u;
        unsigned h1 = u1 & 0xFFFF0000u;
        H.u[i] = (u0 >> 16) | h1;
        L.u[i] = pk_bf16(f[2 * i]     - __uint_as_float(h0),
                         f[2 * i + 1] - __uint_as_float(h1));
    }
    hi = H.v; lo = L.v;
}

// ---------------------------------------------------------------------------
// Kernel 1: g = vertex @ w_vert via split-bf16 MFMA, split-k 2-way.
// Byte-identical to R17 (best-known gemm).
// ---------------------------------------------------------------------------
__global__ __launch_bounds__(256, 4) void gat_gemm_kernel(
    const float* __restrict__ vertex, const float* __restrict__ w_vert,
    const float* __restrict__ attn_w, unsigned short* __restrict__ gT,
    float* __restrict__ ssT, float* __restrict__ sdT)
{
    __shared__ __align__(16) unsigned short bHi[8192];
    __shared__ __align__(16) unsigned short bLo[8192];
    f32x4 (*comb)[4][64] = reinterpret_cast<f32x4(*)[4][64]>(bHi);
    unsigned short (*trans)[72] = reinterpret_cast<unsigned short(*)[72]>(bLo);

    const int t = threadIdx.x, lane = t & 63, wv = t >> 6;
    const int mt = wv & 1, kh = wv >> 1;
    const int il = lane & 15, ql = lane >> 4;
    const int h = blockIdx.y, gr0 = blockIdx.x * 64;
    const int b = gr0 >> 10, bh = b * NH + h;

    {
        const int n  = t & 31;
        const int kb = t >> 5;               // 0..7
        const int il_s = n & 15, nt_s = n >> 4;
        #pragma unroll
        for (int q = 0; q < 4; ++q) {
            const int k0 = kb * 8 + 64 * q;  // 8-aligned, covers 0..255
            const float* wp = w_vert + (size_t)k0 * NOUT + h * 32 + n;
            float f[8];
            #pragma unroll
            for (int j = 0; j < 8; ++j) f[j] = wp[j * NOUT];
            unsigned hu[4], lu[4];
            #pragma unroll
            for (int j2 = 0; j2 < 4; ++j2) {
                unsigned u0 = __float_as_uint(f[2 * j2]);
                unsigned u1 = __float_as_uint(f[2 * j2 + 1]);
                unsigned h0 = u0 & 0xFFFF0000u;
                unsigned h1 = u1 & 0xFFFF0000u;
                hu[j2] = (u0 >> 16) | h1;
                lu[j2] = pk_bf16(f[2 * j2]     - __uint_as_float(h0),
                                 f[2 * j2 + 1] - __uint_as_float(h1));
            }
            const int ktile = k0 >> 5;           // 0..7
            const int qlb   = (k0 & 31) >> 3;    // 0..3
            const int off   = (ktile * 2 + nt_s) * 512 + (qlb * 16 + il_s) * 8;
            *(uint4*)&bHi[off] = *(const uint4*)hu;
            *(uint4*)&bLo[off] = *(const uint4*)lu;
        }
    }
    __syncthreads();

    const float* arow0 = vertex + (size_t)(gr0 + mt * 32 + il) * F_IN + kh * 128 + ql * 8;
    const float* arow1 = arow0 + 16 * F_IN;

    f32x4 c00 = {0.f, 0.f, 0.f, 0.f}, c01 = c00, c10 = c00, c11 = c00;

    #pragma unroll
    for (int kk = 0; kk < 4; ++kk) {
        float4 a0a = *(const float4*)(arow0 + kk * 32);
        float4 a0b = *(const float4*)(arow0 + kk * 32 + 4);
        float4 a1a = *(const float4*)(arow1 + kk * 32);
        float4 a1b = *(const float4*)(arow1 + kk * 32 + 4);

        const int bkb = (kh * 4 + kk) * 2;
        bf16x8 bh0 = *(const bf16x8*)&bHi[bkb * 512 + lane * 8];
        bf16x8 bh1 = *(const bf16x8*)&bHi[(bkb + 1) * 512 + lane * 8];
        bf16x8 bl0 = *(const bf16x8*)&bLo[bkb * 512 + lane * 8];
        bf16x8 bl1 = *(const bf16x8*)&bLo[(bkb + 1) * 512 + lane * 8];

        bf16x8 a0hi, a0lo, a1hi, a1lo;
        split8(a0a, a0b, a0hi, a0lo);
        split8(a1a, a1b, a1hi, a1lo);

        c00 = __builtin_amdgcn_mfma_f32_16x16x32_bf16(a0hi, bh0, c00, 0, 0, 0);
        c01 = __builtin_amdgcn_mfma_f32_16x16x32_bf16(a0hi, bh1, c01, 0, 0, 0);
        c10 = __builtin_amdgcn_mfma_f32_16x16x32_bf16(a1hi, bh0, c10, 0, 0, 0);
        c11 = __builtin_amdgcn_mfma_f32_16x16x32_bf16(a1hi, bh1, c11, 0, 0, 0);
        c00 = __builtin_amdgcn_mfma_f32_16x16x32_bf16(a0lo, bh0, c00, 0, 0, 0);
        c01 = __builtin_amdgcn_mfma_f32_16x16x32_bf16(a0lo, bh1, c01, 0, 0, 0);
        c10 = __builtin_amdgcn_mfma_f32_16x16x32_bf16(a1lo, bh0, c10, 0, 0, 0);
        c11 = __builtin_amdgcn_mfma_f32_16x16x32_bf16(a1lo, bh1, c11, 0, 0, 0);
        c00 = __builtin_amdgcn_mfma_f32_16x16x32_bf16(a0hi, bl0, c00, 0, 0, 0);
        c01 = __builtin_amdgcn_mfma_f32_16x16x32_bf16(a0hi, bl1, c01, 0, 0, 0);
        c10 = __builtin_amdgcn_mfma_f32_16x16x32_bf16(a1hi, bl0, c10, 0, 0, 0);
        c11 = __builtin_amdgcn_mfma_f32_16x16x32_bf16(a1hi, bl1, c11, 0, 0, 0);
    }

    __syncthreads();
    if (kh == 1) {
        comb[mt][0][lane] = c00; comb[mt][1][lane] = c01;
        comb[mt][2][lane] = c10; comb[mt][3][lane] = c11;
    }
    __syncthreads();
    if (kh == 0) {
        c00 = c00 + comb[mt][0][lane]; c01 = c01 + comb[mt][1][lane];
        c10 = c10 + comb[mt][2][lane]; c11 = c11 + comb[mt][3][lane];

        const float wsv0 = attn_w[il],      wsv1 = attn_w[16 + il];
        const float wdv0 = attn_w[ND + il], wdv1 = attn_w[ND + 16 + il];
        const int j0 = (gr0 & 1023) + mt * 32;

        #pragma unroll
        for (int g = 0; g < 2; ++g) {
            f32x4 cA = g ? c10 : c00;   // d = il
            f32x4 cB = g ? c11 : c01;   // d = 16+il
            const int jl = mt * 32 + g * 16 + ql * 4;   // local j in [0,64)

            // transpose into padded LDS — g stored as f16
            *(unsigned*)&trans[il][jl]          = pk_f16(cA[0], cA[1]);
            *(unsigned*)&trans[il][jl + 2]      = pk_f16(cA[2], cA[3]);
            *(unsigned*)&trans[16 + il][jl]     = pk_f16(cB[0], cB[1]);
            *(unsigned*)&trans[16 + il][jl + 2] = pk_f16(cB[2], cB[3]);

            const int jr = j0 + g * 16 + ql * 4;
            #pragma unroll
            for (int reg = 0; reg < 4; ++reg) {
                float ps = cA[reg] * wsv0 + cB[reg] * wsv1;
                float pd = cA[reg] * wdv0 + cB[reg] * wdv1;
                #pragma unroll
                for (int off = 1; off < 16; off <<= 1) {
                    ps += __shfl_xor(ps, off);
                    pd += __shfl_xor(pd, off);
                }
                if (il == 0) {
                    ssT[bh * NN + jr + reg] = ps;
                    sdT[bh * NN + jr + reg] = pd;
                }
            }
        }
    }
    __syncthreads();

    {
        const int d  = t >> 3;
        const int jo = (t & 7) * 8;
        uint4 v = *(const uint4*)&trans[d][jo];
        *(uint4*)(gT + ((size_t)(bh * ND) + d) * NN + (gr0 & 1023) + jo) = v;
    }
}

// ---------------------------------------------------------------------------
// Kernel 2 (exp-free MFMA attn, packed-f16 P path, R21 pipelined loads):
//   R17 structure; kk loop fully unrolled with rotating prefetch buffers:
//   gT (global/L2, ~250cyc) depth 4; Bp/Bn (LDS, ~120cyc) depth 2.
// ---------------------------------------------------------------------------
__global__ __launch_bounds__(256, 4) void gat_attn_kernel(
    const unsigned short* __restrict__ gT, const float* __restrict__ ssT,
    const float* __restrict__ sdT, float* __restrict__ out)
{
    __shared__ __align__(16) unsigned short BpH[NN];   // 2 KB, f16 bits
    __shared__ __align__(16) unsigned short BnH[NN];   // 2 KB, f16 bits
    __shared__ f32x4 ccomb[2][12][64];                 // 24 KB
    __shared__ float red[4];

    const int bid = blockIdx.x;
    const int bh = bid & 63;                 // b*NH + h  (bid%8 = h)
    const int b = bh >> 3, h = bh & 7;
    const int i0 = (bid >> 6) * 64;
    const int t = threadIdx.x, lane = t & 63, jq = t >> 6;
    const int il = lane & 15, ql = lane >> 4;

    // ---- phase 0: BpH/BnH (f16) + global sd max + per-lane i-constants ----
    float sdv[4]; float M = -3.0e38f;
    #pragma unroll
    for (int q = 0; q < 4; ++q) {
        sdv[q] = sdT[bh * NN + t + 256 * q];
        M = fmaxf(M, sdv[q]);
    }
    #pragma unroll
    for (int off = 32; off >= 1; off >>= 1)
        M = fmaxf(M, __shfl_xor(M, off));
    if (lane == 0) red[jq] = M;
    #pragma unroll
    for (int q = 0; q < 4; ++q) {
        union { _Float16 h; unsigned short u; } cp, cn;
        cp.h = (_Float16)exp2f(sdv[q] * LOG2E);
        cn.h = (_Float16)exp2f(0.2f * LOG2E * sdv[q]);
        BpH[t + 256 * q] = cp.u;
        BnH[t + 256 * q] = cn.u;
    }
    __syncthreads();
    M = fmaxf(fmaxf(red[0], red[1]), fmaxf(red[2], red[3]));

    f16x2 apv[4], anv[4];
    #pragma unroll
    for (int mt = 0; mt < 4; ++mt) {
        const float si = ssT[bh * NN + i0 + mt * 16 + il];
        float x = si + M; x = fmaxf(x, 0.2f * x);
        const float mk = x * LOG2E;
        const _Float16 ah = (_Float16)exp2f(fmaf(si, LOG2E, -mk));
        const _Float16 nh = (_Float16)exp2f(fmaf(0.2f * si, LOG2E, -mk));
        apv[mt] = (f16x2){ah, ah};
        anv[mt] = (f16x2){nh, nh};
    }

    const unsigned short* gb0 = gT + ((size_t)(bh * ND) + il) * NN + jq * 256 + ql * 8;
    const unsigned short* gb1 = gb0 + 16 * NN;
    const unsigned short* bpq = BpH + jq * 256 + ql * 8;
    const unsigned short* bnq = BnH + jq * 256 + ql * 8;

    union { f16x8 v; unsigned u[4]; } ones;
    ones.u[0] = ones.u[1] = ones.u[2] = ones.u[3] = 0x3C003C00u;   // f16 1.0

    f32x4 c0[4], c1[4], cs[4];
    #pragma unroll
    for (int mt = 0; mt < 4; ++mt) {
        c0[mt] = (f32x4){0.f, 0.f, 0.f, 0.f};
        c1[mt] = c0[mt]; cs[mt] = c0[mt];
    }

    // ---- main loop: wave jq handles j in [jq*256, jq*256+256) ----
    // Software pipeline: gT (global) prefetch depth 4, Bp/Bn (LDS) depth 2.
    // Fully unrolled; all buffer indices compile-time constant.
    f16x8 b0b[4], b1b[4];
    union { uint4 q; unsigned w[4]; } pwb[2], nwb[2];
    #pragma unroll
    for (int s = 0; s < 4; ++s) {
        b0b[s] = *(const f16x8*)(gb0 + s * 32);
        b1b[s] = *(const f16x8*)(gb1 + s * 32);
    }
    #pragma unroll
    for (int s = 0; s < 2; ++s) {
        pwb[s].q = *(const uint4*)(bpq + s * 32);
        nwb[s].q = *(const uint4*)(bnq + s * 32);
    }

    #pragma unroll
    for (int s = 0; s < 8; ++s) {
        const int gbi = s & 3, lbi = s & 1;
        const f16x8 bf0 = b0b[gbi];
        const f16x8 bf1 = b1b[gbi];
        unsigned pw0 = pwb[lbi].w[0], pw1 = pwb[lbi].w[1];
        unsigned pw2 = pwb[lbi].w[2], pw3 = pwb[lbi].w[3];
        unsigned nw0 = nwb[lbi].w[0], nw1 = nwb[lbi].w[1];
        unsigned nw2 = nwb[lbi].w[2], nw3 = nwb[lbi].w[3];

        if (s < 4) {   // prefetch gT for s+4
            b0b[gbi] = *(const f16x8*)(gb0 + (s + 4) * 32);
            b1b[gbi] = *(const f16x8*)(gb1 + (s + 4) * 32);
        }
        if (s < 6) {   // prefetch Bp/Bn for s+2
            pwb[lbi].q = *(const uint4*)(bpq + (s + 2) * 32);
            nwb[lbi].q = *(const uint4*)(bnq + (s + 2) * 32);
        }

        const unsigned pww[4] = {pw0, pw1, pw2, pw3};
        const unsigned nww[4] = {nw0, nw1, nw2, nw3};
        #pragma unroll
        for (int mt = 0; mt < 4; ++mt) {
            union { f16x8 v; unsigned u[4]; } af;
            #pragma unroll
            for (int u = 0; u < 4; ++u) {
                union { unsigned w; f16x2 v; } p2, n2, e2;
                p2.w = pww[u];
                n2.w = nww[u];
                e2.v = __builtin_elementwise_max(p2.v * apv[mt],
                                                 n2.v * anv[mt]);
                af.u[u] = e2.w;
            }
            c0[mt] = __builtin_amdgcn_mfma_f32_16x16x32_f16(af.v, bf0, c0[mt], 0, 0, 0);
            c1[mt] = __builtin_amdgcn_mfma_f32_16x16x32_f16(af.v, bf1, c1[mt], 0, 0, 0);
            cs[mt] = __builtin_amdgcn_mfma_f32_16x16x32_f16(af.v, ones.v, cs[mt], 0, 0, 0);
        }
    }

    // ---- quarter-combine tree: 2,3 -> 0,1; then 1 -> 0 ----
    if (jq >= 2) {
        #pragma unroll
        for (int mt = 0; mt < 4; ++mt) {
            ccomb[jq - 2][mt * 3 + 0][lane] = c0[mt];
            ccomb[jq - 2][mt * 3 + 1][lane] = c1[mt];
            ccomb[jq - 2][mt * 3 + 2][lane] = cs[mt];
        }
    }
    __syncthreads();
    if (jq < 2) {
        #pragma unroll
        for (int mt = 0; mt < 4; ++mt) {
            c0[mt] = c0[mt] + ccomb[jq][mt * 3 + 0][lane];
            c1[mt] = c1[mt] + ccomb[jq][mt * 3 + 1][lane];
            cs[mt] = cs[mt] + ccomb[jq][mt * 3 + 2][lane];
        }
    }
    __syncthreads();
    if (jq == 1) {
        #pragma unroll
        for (int mt = 0; mt < 4; ++mt) {
            ccomb[0][mt * 3 + 0][lane] = c0[mt];
            ccomb[0][mt * 3 + 1][lane] = c1[mt];
            ccomb[0][mt * 3 + 2][lane] = cs[mt];
        }
    }
    __syncthreads();
    if (jq == 0) {
        #pragma unroll
        for (int mt = 0; mt < 4; ++mt) {
            c0[mt] = c0[mt] + ccomb[0][mt * 3 + 0][lane];
            c1[mt] = c1[mt] + ccomb[0][mt * 3 + 1][lane];
            cs[mt] = cs[mt] + ccomb[0][mt * 3 + 2][lane];

            // C/D: col=il (d), row=ql*4+reg (i); cs[mt][reg] = S_i
            float* ob = out + (size_t)(b * NN + i0 + mt * 16 + ql * 4) * NOUT + h * ND + il;
            #pragma unroll
            for (int reg = 0; reg < 4; ++reg) {
                const float r = 1.0f / cs[mt][reg];
                ob[reg * NOUT]      = c0[mt][reg] * r;
                ob[reg * NOUT + 16] = c1[mt][reg] * r;
            }
        }
    }
}

// ---------------------------------------------------------------------------
extern "C" void kernel_launch(void* const* d_in, const int* in_sizes, int n_in,
                              void* d_out, int out_size, void* d_ws, size_t ws_size,
                              hipStream_t stream) {
    (void)in_sizes; (void)n_in; (void)out_size; (void)ws_size;
    const float* vertex = (const float*)d_in[0];
    const float* w_vert = (const float*)d_in[1];
    const float* attn_w = (const float*)d_in[2];
    float* out = (float*)d_out;

    char* ws = (char*)d_ws;
    unsigned short* gT = (unsigned short*)ws;                          // 4 MB
    float* ssT = (float*)(ws + ((size_t)NB * NH * ND * NN * 2));
    float* sdT = ssT + (size_t)NB * NH * NN;

    gat_gemm_kernel<<<dim3(128, NH), 256, 0, stream>>>(vertex, w_vert, attn_w,
                                                       gT, ssT, sdT);
    gat_attn_kernel<<<1024, 256, 0, stream>>>(gT, ssT, sdT, out);
}